// Round 9
// baseline (369.057 us; speedup 1.0000x reference)
//
#include <hip/hip_runtime.h>
#include <hip/hip_bf16.h>
#include <cstdint>

// Problem constants
#define B_   2
#define S_   512
#define N_   20000
#define H_   3
#define C_   128
#define E_   320000
#define DG_  128
#define D_   384
#define BN_  (B_ * N_)            // 40000
#define F_   (H_ * C_)            // 384
#define ECSR_ (E_ + N_)           // 340000 (per-graph CSR: E edges + N self-loops)

#define MPADQ 20096               // N_ padded to 128
#define MPADL 40064               // BN_ padded to 128

// split-K for proj2 GEMM (K = N_ = 20000 = 625 * 32)
#define PNS2 32
#define PCH2 640                  // 20 k-iters per split (last split: 160)

using short8  = __attribute__((ext_vector_type(8))) short;
using floatx4 = __attribute__((ext_vector_type(4))) float;

__device__ __forceinline__ float b2f(unsigned short u) {
  union { unsigned int i; float f; } x; x.i = ((unsigned int)u) << 16; return x.f;
}
__device__ __forceinline__ unsigned short f2b(float f) {
  __hip_bfloat16 b = __float2bfloat16(f);
  return *reinterpret_cast<unsigned short*>(&b);
}

// ================= fused conversion + epilogue-precompute kernel =================
struct bf4 { __hip_bfloat16 a, b, c, d; };

#define NWQ4 ((MPADQ * 512) / 4)        // 2,572,288
#define NXE4 ((B_ * S_ * D_) / 4)       //    98,304
#define NWL4 ((F_ * D_) / 4)            //    36,864
#define NWP4 ((S_ * N_) / 4)            // 2,560,000
#define NWT4 ((DG_ * F_) / 4)           //    12,288
#define NCV0 NWQ4
#define NCV1 (NCV0 + NXE4)
#define NCV2 (NCV1 + NWL4)
#define NCV3 (NCV2 + NWP4)
#define NCV4 (NCV3 + NWT4)              // 5,279,744 (multiple of 64)
#define NCVTOT (NCV4 + (F_ + DG_) * 64) // + prep waves: 5,312,512 (mult of 256)

__device__ __forceinline__ void cv4(const float* __restrict__ src,
                                    __hip_bfloat16* __restrict__ dst, int e) {
  float4 v = *(const float4*)(src + e);
  bf4 r{__float2bfloat16(v.x), __float2bfloat16(v.y),
        __float2bfloat16(v.z), __float2bfloat16(v.w)};
  *(bf4*)(dst + e) = r;
}

// epi[0][f] = sum_d Wlin[f,d]          (multiplies bq[n])
// epi[1][f] = sum_d Wm[d]*Wlin[f,d]    (multiplies mask[b,n])
// epi[2][f] = sum_d bm[d]*Wlin[f,d]    (constant)
// swt[g]    = sum_f Wtemp[g,f]         (multiplies bproj[s] in init_out)
__global__ __launch_bounds__(256) void conv_all_kernel(
    const float* __restrict__ Wq,    __hip_bfloat16* __restrict__ WqB,
    const float* __restrict__ xe,    __hip_bfloat16* __restrict__ xeB,
    const float* __restrict__ Wlin,  __hip_bfloat16* __restrict__ WlinB,
    const float* __restrict__ Wproj, __hip_bfloat16* __restrict__ WprojB,
    const float* __restrict__ Wtemp, __hip_bfloat16* __restrict__ WtempB,
    const float* __restrict__ Wm,    const float* __restrict__ bm,
    float* __restrict__ epi,         float* __restrict__ swt) {
  int idx = blockIdx.x * 256 + threadIdx.x;
  if (idx < NCV0) {
    int e = idx * 4;
    int row = e >> 9;                       // Wq row (ld 512)
    float4 v = make_float4(0.f, 0.f, 0.f, 0.f);
    if (row < N_) v = *(const float4*)(Wq + e);
    bf4 r{__float2bfloat16(v.x), __float2bfloat16(v.y),
          __float2bfloat16(v.z), __float2bfloat16(v.w)};
    *(bf4*)(WqB + e) = r;
  } else if (idx < NCV1) {
    cv4(xe, xeB, (idx - NCV0) * 4);
  } else if (idx < NCV2) {
    cv4(Wlin, WlinB, (idx - NCV1) * 4);
  } else if (idx < NCV3) {
    cv4(Wproj, WprojB, (idx - NCV2) * 4);
  } else if (idx < NCV4) {
    cv4(Wtemp, WtempB, (idx - NCV3) * 4);
  } else {
    // prep region: wave-aligned (NCV4 % 64 == 0); one wave per output row
    int w = (idx - NCV4) >> 6;
    int lane = idx & 63;
    if (w < F_) {
      float s0 = 0.f, s1 = 0.f, s2 = 0.f;
      const float* row = Wlin + (size_t)w * D_;
      for (int d = lane; d < D_; d += 64) {
        float wv = row[d];
        s0 += wv; s1 += Wm[d] * wv; s2 += bm[d] * wv;
      }
#pragma unroll
      for (int o = 32; o > 0; o >>= 1) {
        s0 += __shfl_down(s0, o); s1 += __shfl_down(s1, o); s2 += __shfl_down(s2, o);
      }
      if (lane == 0) { epi[w] = s0; epi[F_ + w] = s1; epi[2 * F_ + w] = s2; }
    } else {
      int g = w - F_;
      float s = 0.f;
      const float* row = Wtemp + (size_t)g * F_;
      for (int f = lane; f < F_; f += 64) s += row[f];
#pragma unroll
      for (int o = 32; o > 0; o >>= 1) s += __shfl_down(s, o);
      if (lane == 0) swt[g] = s;
    }
  }
}

// ================= bf16 MFMA GEMM (NT: A[m][k], Bt[n][k], both k-major) =================
// EPI=1: xp epilogue  v += bq[rg]*epi[cg] + mask[bz*N+rg]*epi[F+cg] + epi[2F+cg]
template <int EPI>
__global__ __launch_bounds__(256) void mfma_gemm_nt(
    const __hip_bfloat16* __restrict__ A, const __hip_bfloat16* __restrict__ Bt,
    __hip_bfloat16* __restrict__ Cout, int K, int Mvalid, int ldc,
    size_t bstrideB, size_t bstrideC,
    const float* __restrict__ bq, const float* __restrict__ mask,
    const float* __restrict__ epi) {
  const int tid = threadIdx.x;
  const int m0 = blockIdx.x * 128;
  const int n0 = blockIdx.y * 128;
  const int bz = blockIdx.z;

  const unsigned short* Ap = (const unsigned short*)A;
  const unsigned short* Bp = (const unsigned short*)(Bt + bstrideB * bz);

  __shared__ __align__(16) unsigned short As[128][40];
  __shared__ __align__(16) unsigned short Bs[128][40];

  const int wave = tid >> 6, lane = tid & 63;
  const int wm = (wave & 1) * 64, wn = (wave >> 1) * 64;
  const int lrow = lane & 15, lk = (lane >> 4) * 8;

  const int srow = tid >> 2;            // 0..63
  const int skoff = (tid & 3) * 8;      // 0,8,16,24

  floatx4 acc[4][4];
#pragma unroll
  for (int i = 0; i < 4; ++i)
#pragma unroll
    for (int j = 0; j < 4; ++j) acc[i][j] = floatx4{0.f, 0.f, 0.f, 0.f};

  for (int k0 = 0; k0 < K; k0 += 32) {
    int4 av0 = *(const int4*)(Ap + (size_t)(m0 + srow) * K + k0 + skoff);
    int4 av1 = *(const int4*)(Ap + (size_t)(m0 + 64 + srow) * K + k0 + skoff);
    int4 bv0 = *(const int4*)(Bp + (size_t)(n0 + srow) * K + k0 + skoff);
    int4 bv1 = *(const int4*)(Bp + (size_t)(n0 + 64 + srow) * K + k0 + skoff);
    __syncthreads();
    *(int4*)&As[srow][skoff] = av0;
    *(int4*)&As[64 + srow][skoff] = av1;
    *(int4*)&Bs[srow][skoff] = bv0;
    *(int4*)&Bs[64 + srow][skoff] = bv1;
    __syncthreads();
    short8 af[4], bf[4];
#pragma unroll
    for (int mt = 0; mt < 4; ++mt)
      af[mt] = *(const short8*)&As[wm + mt * 16 + lrow][lk];
#pragma unroll
    for (int nt = 0; nt < 4; ++nt)
      bf[nt] = *(const short8*)&Bs[wn + nt * 16 + lrow][lk];
#pragma unroll
    for (int mt = 0; mt < 4; ++mt)
#pragma unroll
      for (int nt = 0; nt < 4; ++nt)
        acc[mt][nt] = __builtin_amdgcn_mfma_f32_16x16x32_bf16(af[mt], bf[nt],
                                                              acc[mt][nt], 0, 0, 0);
  }

  __hip_bfloat16* Cb = Cout + bstrideC * bz;
#pragma unroll
  for (int mt = 0; mt < 4; ++mt) {
#pragma unroll
    for (int r = 0; r < 4; ++r) {
      int rg = m0 + wm + mt * 16 + (lane >> 4) * 4 + r;
      if (rg < Mvalid) {
        float bqv = 0.f, mkv = 0.f;
        if (EPI) {
          bqv = bq[rg];
          mkv = mask[bz * N_ + rg];
        }
#pragma unroll
        for (int nt = 0; nt < 4; ++nt) {
          int cg = n0 + wn + nt * 16 + lrow;
          float v = acc[mt][nt][r];
          if (EPI) v += bqv * epi[cg] + mkv * epi[F_ + cg] + epi[2 * F_ + cg];
          Cb[(size_t)rg * ldc + cg] = __float2bfloat16(v);
        }
      }
    }
  }
}

// ================= gn = gat · Wtemp^T, output TRANSPOSED to gnT [b][g][n] =================
// A = gat [MPADL][F] (rows >= BN_ zeroed, discarded), B = WtempB [DG][F], K=F
__global__ __launch_bounds__(256) void gemm_gn(
    const __hip_bfloat16* __restrict__ A, const __hip_bfloat16* __restrict__ Bt,
    __hip_bfloat16* __restrict__ gnT) {
  const int tid = threadIdx.x;
  const int m0 = blockIdx.x * 128;

  const unsigned short* Ap = (const unsigned short*)A;
  const unsigned short* Bp = (const unsigned short*)Bt;

  __shared__ __align__(16) unsigned short As[128][40];
  __shared__ __align__(16) unsigned short Bs[128][40];

  const int wave = tid >> 6, lane = tid & 63;
  const int wm = (wave & 1) * 64, wn = (wave >> 1) * 64;
  const int lrow = lane & 15, lk = (lane >> 4) * 8;
  const int srow = tid >> 2;
  const int skoff = (tid & 3) * 8;

  floatx4 acc[4][4];
#pragma unroll
  for (int i = 0; i < 4; ++i)
#pragma unroll
    for (int j = 0; j < 4; ++j) acc[i][j] = floatx4{0.f, 0.f, 0.f, 0.f};

  for (int k0 = 0; k0 < F_; k0 += 32) {
    int4 av0 = *(const int4*)(Ap + (size_t)(m0 + srow) * F_ + k0 + skoff);
    int4 av1 = *(const int4*)(Ap + (size_t)(m0 + 64 + srow) * F_ + k0 + skoff);
    int4 bv0 = *(const int4*)(Bp + (size_t)(srow) * F_ + k0 + skoff);
    int4 bv1 = *(const int4*)(Bp + (size_t)(64 + srow) * F_ + k0 + skoff);
    __syncthreads();
    *(int4*)&As[srow][skoff] = av0;
    *(int4*)&As[64 + srow][skoff] = av1;
    *(int4*)&Bs[srow][skoff] = bv0;
    *(int4*)&Bs[64 + srow][skoff] = bv1;
    __syncthreads();
    short8 af[4], bf[4];
#pragma unroll
    for (int mt = 0; mt < 4; ++mt)
      af[mt] = *(const short8*)&As[wm + mt * 16 + lrow][lk];
#pragma unroll
    for (int nt = 0; nt < 4; ++nt)
      bf[nt] = *(const short8*)&Bs[wn + nt * 16 + lrow][lk];
#pragma unroll
    for (int mt = 0; mt < 4; ++mt)
#pragma unroll
      for (int nt = 0; nt < 4; ++nt)
        acc[mt][nt] = __builtin_amdgcn_mfma_f32_16x16x32_bf16(af[mt], bf[nt],
                                                              acc[mt][nt], 0, 0, 0);
  }

  // transposed store: 4 consecutive rows (one r-group) -> 4 consecutive n in gnT
#pragma unroll
  for (int mt = 0; mt < 4; ++mt) {
    int rg0 = m0 + wm + mt * 16 + (lane >> 4) * 4;
    if (rg0 < BN_) {                      // rg0 mult of 4, BN_/N_ mult of 4
      int b = (rg0 >= N_) ? 1 : 0;
      int n = rg0 - b * N_;
#pragma unroll
      for (int nt = 0; nt < 4; ++nt) {
        int cg = wn + nt * 16 + lrow;     // 0..127
        ushort4 o;
        o.x = f2b(acc[mt][nt][0]); o.y = f2b(acc[mt][nt][1]);
        o.z = f2b(acc[mt][nt][2]); o.w = f2b(acc[mt][nt][3]);
        *(ushort4*)((unsigned short*)gnT + (size_t)b * DG_ * N_ + (size_t)cg * N_ + n) = o;
      }
    }
  }
}

// ================= proj2: Wproj · gn^T, split-K, atomicAdd into out =================
// A = WprojB [S][N_], B = gnT[b] [DG][N_]; out pre-initialized with bias by init_out.
__global__ __launch_bounds__(256) void gemm_proj2(
    const __hip_bfloat16* __restrict__ A, const __hip_bfloat16* __restrict__ Bt,
    float* __restrict__ out) {
  const int tid = threadIdx.x;
  const int m0 = blockIdx.x * 128;       // s tile
  const int bz = blockIdx.z;             // b*PNS2 + ks
  const int b = bz / PNS2, ks = bz - b * PNS2;
  const int kbeg = ks * PCH2;
  const int kend = (kbeg + PCH2 < N_) ? (kbeg + PCH2) : N_;

  const unsigned short* Ap = (const unsigned short*)A;
  const unsigned short* Bp = (const unsigned short*)(Bt + (size_t)b * DG_ * N_);

  __shared__ __align__(16) unsigned short As[128][40];
  __shared__ __align__(16) unsigned short Bs[128][40];

  const int wave = tid >> 6, lane = tid & 63;
  const int wm = (wave & 1) * 64, wn = (wave >> 1) * 64;
  const int lrow = lane & 15, lk = (lane >> 4) * 8;
  const int srow = tid >> 2;
  const int skoff = (tid & 3) * 8;

  floatx4 acc[4][4];
#pragma unroll
  for (int i = 0; i < 4; ++i)
#pragma unroll
    for (int j = 0; j < 4; ++j) acc[i][j] = floatx4{0.f, 0.f, 0.f, 0.f};

  for (int k0 = kbeg; k0 < kend; k0 += 32) {
    int4 av0 = *(const int4*)(Ap + (size_t)(m0 + srow) * N_ + k0 + skoff);
    int4 av1 = *(const int4*)(Ap + (size_t)(m0 + 64 + srow) * N_ + k0 + skoff);
    int4 bv0 = *(const int4*)(Bp + (size_t)(srow) * N_ + k0 + skoff);
    int4 bv1 = *(const int4*)(Bp + (size_t)(64 + srow) * N_ + k0 + skoff);
    __syncthreads();
    *(int4*)&As[srow][skoff] = av0;
    *(int4*)&As[64 + srow][skoff] = av1;
    *(int4*)&Bs[srow][skoff] = bv0;
    *(int4*)&Bs[64 + srow][skoff] = bv1;
    __syncthreads();
    short8 af[4], bf[4];
#pragma unroll
    for (int mt = 0; mt < 4; ++mt)
      af[mt] = *(const short8*)&As[wm + mt * 16 + lrow][lk];
#pragma unroll
    for (int nt = 0; nt < 4; ++nt)
      bf[nt] = *(const short8*)&Bs[wn + nt * 16 + lrow][lk];
#pragma unroll
    for (int mt = 0; mt < 4; ++mt)
#pragma unroll
      for (int nt = 0; nt < 4; ++nt)
        acc[mt][nt] = __builtin_amdgcn_mfma_f32_16x16x32_bf16(af[mt], bf[nt],
                                                              acc[mt][nt], 0, 0, 0);
  }

  float* op = out + (size_t)b * S_ * DG_;
#pragma unroll
  for (int mt = 0; mt < 4; ++mt) {
#pragma unroll
    for (int r = 0; r < 4; ++r) {
      int rg = m0 + wm + mt * 16 + (lane >> 4) * 4 + r;   // < 512 always
#pragma unroll
      for (int nt = 0; nt < 4; ++nt) {
        int cg = wn + nt * 16 + lrow;                      // < 128
        atomicAdd(&op[(size_t)rg * DG_ + cg], acc[mt][nt][r]);
      }
    }
  }
}

// out[b,s,g] = btemp[g] + bproj[s]*swt[g]  (bias pre-load; proj2 accumulates on top)
__global__ __launch_bounds__(128) void init_out_kernel(
    const float* __restrict__ bproj, const float* __restrict__ swt,
    const float* __restrict__ btemp, float* __restrict__ out) {
  int bs = blockIdx.x;
  int s = bs & (S_ - 1);
  int g = threadIdx.x;
  out[(size_t)bs * DG_ + g] = btemp[g] + bproj[s] * swt[g];
}

// ---------------- attention coefficients ----------------
__global__ __launch_bounds__(256) void att_kernel(
    const __hip_bfloat16* __restrict__ xp, const float* __restrict__ att_src,
    const float* __restrict__ att_dst, float* __restrict__ a_src,
    float* __restrict__ a_dst) {
  int gid = blockIdx.x * blockDim.x + threadIdx.x;
  int wid = gid >> 6;
  int lane = threadIdx.x & 63;
  if (wid >= BN_ * H_) return;
  int i = wid / H_, h = wid - i * H_;
  const __hip_bfloat16* row = xp + (size_t)i * F_ + h * C_;
  const float* as = att_src + h * C_;
  const float* ad = att_dst + h * C_;
  float v0 = __bfloat162float(row[lane]), v1 = __bfloat162float(row[lane + 64]);
  float s1 = v0 * as[lane] + v1 * as[lane + 64];
  float s2 = v0 * ad[lane] + v1 * ad[lane + 64];
#pragma unroll
  for (int off = 32; off > 0; off >>= 1) {
    s1 += __shfl_down(s1, off);
    s2 += __shfl_down(s2, off);
  }
  if (lane == 0) {
    a_src[i * H_ + h] = s1;
    a_dst[i * H_ + h] = s2;
  }
}

// ---------------- CSR build (per-graph: N nodes, E edges; shared by both batches) ----
__global__ __launch_bounds__(256) void count_kernel(const int* __restrict__ ei,
                                                    int* __restrict__ counts,
                                                    int* __restrict__ rank) {
  int idx = blockIdx.x * blockDim.x + threadIdx.x;
  if (idx >= E_) return;
  int d = ei[E_ + idx];
  rank[idx] = atomicAdd(&counts[d], 1);
}

// hierarchical scan over N_: scan1 (per-block) -> scan2 (block bases) -> scan3 (add)
#define SCB 1024
#define NSCB ((N_ + SCB - 1) / SCB)     // 20
__global__ __launch_bounds__(1024) void scan1_kernel(const int* __restrict__ counts,
                                                     int* __restrict__ offs,
                                                     int* __restrict__ btot) {
  __shared__ int wsum[16];
  int t = threadIdx.x, wave = t >> 6, lane = t & 63;
  int i = blockIdx.x * SCB + t;
  int v = (i < N_) ? (counts[i] + 1) : 0;  // +1 = self loop
  int x = v;
#pragma unroll
  for (int o = 1; o < 64; o <<= 1) {
    int y = __shfl_up(x, o);
    if (lane >= o) x += y;
  }
  if (lane == 63) wsum[wave] = x;
  __syncthreads();
  if (wave == 0) {
    int w = (lane < 16) ? wsum[lane] : 0;
#pragma unroll
    for (int o = 1; o < 16; o <<= 1) {
      int y = __shfl_up(w, o);
      if (lane >= o) w += y;
    }
    if (lane < 16) wsum[lane] = w;
  }
  __syncthreads();
  int woff = (wave == 0) ? 0 : wsum[wave - 1];
  if (i < N_) offs[i] = woff + x - v;      // exclusive within block
  if (t == 0) btot[blockIdx.x] = wsum[15];
}

__global__ __launch_bounds__(64) void scan2_kernel(int* __restrict__ btot) {
  int lane = threadIdx.x;
  int v = (lane < NSCB) ? btot[lane] : 0;
  int x = v;
#pragma unroll
  for (int o = 1; o < 64; o <<= 1) {
    int y = __shfl_up(x, o);
    if (lane >= o) x += y;
  }
  if (lane < NSCB) btot[lane] = x - v;      // exclusive base
}

__global__ __launch_bounds__(256) void scan3_kernel(int* __restrict__ offs,
                                                    const int* __restrict__ btot) {
  int i = blockIdx.x * 256 + threadIdx.x;
  if (i < N_) offs[i] += btot[i >> 10];
}

__global__ __launch_bounds__(256) void fill_kernel(
    const int* __restrict__ ei, const int* __restrict__ rank,
    const int* __restrict__ offs, const int* __restrict__ counts,
    int* __restrict__ col) {
  int idx = blockIdx.x * blockDim.x + threadIdx.x;
  if (idx >= ECSR_) return;
  if (idx < E_) {
    int sg = ei[idx];
    int dg = ei[E_ + idx];
    col[offs[dg] + rank[idx]] = sg;     // local src index
  } else {
    int n = idx - E_;
    col[offs[n] + counts[n]] = n;       // self loop
  }
}

// ---------------- aggregation: one (node, batch) per block; inline softmax -------
// blockIdx 0..N-1: batch 0, N..2N-1: batch 1 (batch-contiguous dispatch keeps each
// 15.4MB xp half hot). 96 active threads: thread t covers xp columns [t*4, t*4+4),
// head h = t/32. Denominator is free: all 32 threads of a head-group compute the
// identical w per edge. 8-deep unroll for outstanding-load depth.
__global__ __launch_bounds__(128) void agg_kernel(
    const int* __restrict__ offs, const int* __restrict__ counts,
    const int* __restrict__ col, const float* __restrict__ a_src,
    const float* __restrict__ a_dst, const __hip_bfloat16* __restrict__ xp,
    const float* __restrict__ bias_gat, __hip_bfloat16* __restrict__ out) {
  int bi = blockIdx.x;
  int q = (bi >= N_) ? 1 : 0;
  int n = bi - q * N_;
  int qn = q * N_;
  int i = qn + n;
  int t = threadIdx.x;
  if (t >= 96) return;
  int beg = offs[n];
  int nE = counts[n] + 1;
  int h = t >> 5;

  const ushort4* xp4 = (const ushort4*)xp;   // row stride 96 ushort4
  float ad = a_dst[(size_t)i * 3 + h];
  float ax = 0.f, ay = 0.f, az = 0.f, aw = 0.f, sw = 0.f;

  int j = 0;
  for (; j + 8 <= nE; j += 8) {
    int s[8];
    float w[8];
    ushort4 v[8];
#pragma unroll
    for (int u = 0; u < 8; ++u) s[u] = col[beg + j + u] + qn;
#pragma unroll
    for (int u = 0; u < 8; ++u) {
      float e = a_src[(size_t)s[u] * 3 + h] + ad;
      e = (e > 0.f) ? e : 0.2f * e;
      w[u] = __expf(e);
    }
#pragma unroll
    for (int u = 0; u < 8; ++u) v[u] = xp4[(size_t)s[u] * 96 + t];
#pragma unroll
    for (int u = 0; u < 8; ++u) {
      sw += w[u];
      ax = fmaf(w[u], b2f(v[u].x), ax); ay = fmaf(w[u], b2f(v[u].y), ay);
      az = fmaf(w[u], b2f(v[u].z), az); aw = fmaf(w[u], b2f(v[u].w), aw);
    }
  }
  for (; j + 4 <= nE; j += 4) {
    int s0 = col[beg + j + 0] + qn;
    int s1 = col[beg + j + 1] + qn;
    int s2 = col[beg + j + 2] + qn;
    int s3 = col[beg + j + 3] + qn;
    float e0 = a_src[(size_t)s0 * 3 + h] + ad;
    float e1 = a_src[(size_t)s1 * 3 + h] + ad;
    float e2 = a_src[(size_t)s2 * 3 + h] + ad;
    float e3 = a_src[(size_t)s3 * 3 + h] + ad;
    e0 = (e0 > 0.f) ? e0 : 0.2f * e0;
    e1 = (e1 > 0.f) ? e1 : 0.2f * e1;
    e2 = (e2 > 0.f) ? e2 : 0.2f * e2;
    e3 = (e3 > 0.f) ? e3 : 0.2f * e3;
    float w0 = __expf(e0), w1 = __expf(e1);
    float w2 = __expf(e2), w3 = __expf(e3);
    sw += (w0 + w1) + (w2 + w3);
    ushort4 v0 = xp4[(size_t)s0 * 96 + t];
    ushort4 v1 = xp4[(size_t)s1 * 96 + t];
    ushort4 v2 = xp4[(size_t)s2 * 96 + t];
    ushort4 v3 = xp4[(size_t)s3 * 96 + t];
    ax = fmaf(w0, b2f(v0.x), ax); ay = fmaf(w0, b2f(v0.y), ay);
    az = fmaf(w0, b2f(v0.z), az); aw = fmaf(w0, b2f(v0.w), aw);
    ax = fmaf(w1, b2f(v1.x), ax); ay = fmaf(w1, b2f(v1.y), ay);
    az = fmaf(w1, b2f(v1.z), az); aw = fmaf(w1, b2f(v1.w), aw);
    ax = fmaf(w2, b2f(v2.x), ax); ay = fmaf(w2, b2f(v2.y), ay);
    az = fmaf(w2, b2f(v2.z), az); aw = fmaf(w2, b2f(v2.w), aw);
    ax = fmaf(w3, b2f(v3.x), ax); ay = fmaf(w3, b2f(v3.y), ay);
    az = fmaf(w3, b2f(v3.z), az); aw = fmaf(w3, b2f(v3.w), aw);
  }
  for (; j < nE; ++j) {
    int s0 = col[beg + j] + qn;
    float e0 = a_src[(size_t)s0 * 3 + h] + ad;
    e0 = (e0 > 0.f) ? e0 : 0.2f * e0;
    float w0 = __expf(e0);
    sw += w0;
    ushort4 v0 = xp4[(size_t)s0 * 96 + t];
    ax = fmaf(w0, b2f(v0.x), ax); ay = fmaf(w0, b2f(v0.y), ay);
    az = fmaf(w0, b2f(v0.z), az); aw = fmaf(w0, b2f(v0.w), aw);
  }

  float r = 1.0f / sw;
  const float4 bg = *(const float4*)(bias_gat + t * 4);
  ushort4 o;
  o.x = f2b(ax * r + bg.x);
  o.y = f2b(ay * r + bg.y);
  o.z = f2b(az * r + bg.z);
  o.w = f2b(aw * r + bg.w);
  *(ushort4*)((unsigned short*)out + (size_t)i * F_ + t * 4) = o;
}

// ---------------- launcher ----------------
extern "C" void kernel_launch(void* const* d_in, const int* in_sizes, int n_in,
                              void* d_out, int out_size, void* d_ws, size_t ws_size,
                              hipStream_t stream) {
  const float* x_enc   = (const float*)d_in[0];
  const float* mask    = (const float*)d_in[1];
  const int*   ei      = (const int*)d_in[2];
  const float* Wq      = (const float*)d_in[3];
  const float* bq      = (const float*)d_in[4];
  const float* Wm      = (const float*)d_in[5];
  const float* bm      = (const float*)d_in[6];
  const float* Wlin    = (const float*)d_in[7];
  const float* att_src = (const float*)d_in[8];
  const float* att_dst = (const float*)d_in[9];
  const float* bias_gat= (const float*)d_in[10];
  const float* Wproj   = (const float*)d_in[11];
  const float* bproj   = (const float*)d_in[12];
  const float* Wtemp   = (const float*)d_in[13];
  const float* btemp   = (const float*)d_in[14];
  float* outp = (float*)d_out;

  char* ws = (char*)d_ws;
  size_t off = 0;
  auto alloc = [&](size_t bytes) {
    char* p = ws + off;
    off = (off + bytes + 255) & ~(size_t)255;
    return p;
  };

  // regionA timeline:
  //   phase 1 (conv/gemm_q):  Wq_b bf16 [0, 20.58M)
  //   phase 2 (gemm_gn):      gnT bf16 [0, 10.24M)   (Wq_b dead after gemm_q)
  char* regionA = alloc((size_t)MPADQ * S_ * 2);               // 20.58 MB
  __hip_bfloat16* Wq_b = (__hip_bfloat16*)regionA;
  __hip_bfloat16* gnT  = (__hip_bfloat16*)regionA;

  __hip_bfloat16* xeB    = (__hip_bfloat16*)alloc((size_t)B_ * S_ * D_ * 2);
  __hip_bfloat16* yT     = (__hip_bfloat16*)alloc((size_t)B_ * F_ * S_ * 2);
  __hip_bfloat16* xp     = (__hip_bfloat16*)alloc((size_t)BN_ * F_ * 2);
  __hip_bfloat16* gat    = (__hip_bfloat16*)alloc((size_t)MPADL * F_ * 2);  // padded rows
  __hip_bfloat16* WlinB  = (__hip_bfloat16*)alloc((size_t)F_ * D_ * 2);
  __hip_bfloat16* WprojB = (__hip_bfloat16*)alloc((size_t)S_ * N_ * 2);
  __hip_bfloat16* WtempB = (__hip_bfloat16*)alloc((size_t)DG_ * F_ * 2);
  float* epi   = (float*)alloc((size_t)3 * F_ * 4);
  float* swt   = (float*)alloc((size_t)DG_ * 4);
  float* a_src = (float*)alloc((size_t)BN_ * H_ * 4);
  float* a_dst = (float*)alloc((size_t)BN_ * H_ * 4);
  int* counts  = (int*)alloc((size_t)N_ * 4);
  int* offsb   = (int*)alloc((size_t)N_ * 4);
  int* rank    = (int*)alloc((size_t)E_ * 4);
  int* col     = (int*)alloc((size_t)ECSR_ * 4);
  int* btot    = (int*)alloc((size_t)NSCB * 4);
  if (off > ws_size) return;  // workspace too small: fail loudly via absmax

  hipMemsetAsync(counts, 0, (size_t)N_ * 4, stream);
  // zero gat pad rows (read by gemm_gn A-loads, outputs discarded)
  hipMemsetAsync(gat + (size_t)BN_ * F_, 0, (size_t)(MPADL - BN_) * F_ * 2, stream);

  // CSR skeleton (per-graph; independent of everything else)
  count_kernel<<<(E_ + 255) / 256, 256, 0, stream>>>(ei, counts, rank);
  scan1_kernel<<<NSCB, SCB, 0, stream>>>(counts, offsb, btot);
  scan2_kernel<<<1, 64, 0, stream>>>(btot);
  scan3_kernel<<<(N_ + 255) / 256, 256, 0, stream>>>(offsb, btot);
  fill_kernel<<<(ECSR_ + 255) / 256, 256, 0, stream>>>(ei, rank, offsb, counts, col);

  // conversions + epilogue-vector precompute (one fused launch)
  conv_all_kernel<<<NCVTOT / 256, 256, 0, stream>>>(
      Wq, Wq_b, x_enc, xeB, Wlin, WlinB, Wproj, WprojB, Wtemp, WtempB,
      Wm, bm, epi, swt);

  // y^T[b][f][s] = sum_d Wlin[f,d] * xe[b,s,d]   (tiny GEMM, 0.3 GF)
  mfma_gemm_nt<0><<<dim3(F_ / 128, S_ / 128, B_), 256, 0, stream>>>(
      WlinB, xeB, yT, D_, F_, S_, (size_t)S_ * D_, (size_t)F_ * S_,
      nullptr, nullptr, nullptr);
  // xp[b,n,f] = sum_s Wq[n,s]*y[b,s,f] + bq[n]*sWl[f] + mask[b,n]*wmW[f] + bmW[f]
  mfma_gemm_nt<1><<<dim3(MPADQ / 128, F_ / 128, B_), 256, 0, stream>>>(
      Wq_b, yT, xp, S_, N_, F_, (size_t)F_ * S_, (size_t)N_ * F_,
      bq, mask, epi);

  att_kernel<<<(BN_ * H_ + 3) / 4, 256, 0, stream>>>(xp, att_src, att_dst, a_src, a_dst);
  agg_kernel<<<BN_, 128, 0, stream>>>(offsb, counts, col, a_src, a_dst,
                                      xp, bias_gat, gat);

  // gn^T[b][g][n] = sum_f gat[b,n,f] * Wtemp[g,f]   (3.9 GF, transposed store)
  gemm_gn<<<dim3(MPADL / 128, 1, 1), 256, 0, stream>>>(gat, WtempB, gnT);
  // out = bias, then proj2 accumulates split-K contributions via atomicAdd
  init_out_kernel<<<B_ * S_, 128, 0, stream>>>(bproj, swt, btemp, outp);
  gemm_proj2<<<dim3(S_ / 128, 1, B_ * PNS2), 256, 0, stream>>>(WprojB, gnT, outp);
}

// Round 10
// 346.102 us; speedup vs baseline: 1.0663x; 1.0663x over previous
//
#include <hip/hip_runtime.h>
#include <hip/hip_bf16.h>
#include <cstdint>

// Problem constants
#define B_   2
#define S_   512
#define N_   20000
#define H_   3
#define C_   128
#define E_   320000
#define DG_  128
#define D_   384
#define BN_  (B_ * N_)            // 40000
#define F_   (H_ * C_)            // 384
#define ECSR_ (E_ + N_)           // 340000 (per-graph CSR: E edges + N self-loops)

#define MPADQ 20096               // N_ padded to 128
#define MPADL 40064               // BN_ padded to 128

// split-K for proj2 GEMM (K = N_ = 20000 = 625 * 32)
#define PNS2 32
#define PCH2 640                  // 20 k-iters per split (last split: 160)

using short8  = __attribute__((ext_vector_type(8))) short;
using floatx4 = __attribute__((ext_vector_type(4))) float;

__device__ __forceinline__ float b2f(unsigned short u) {
  union { unsigned int i; float f; } x; x.i = ((unsigned int)u) << 16; return x.f;
}
__device__ __forceinline__ unsigned short f2b(float f) {
  __hip_bfloat16 b = __float2bfloat16(f);
  return *reinterpret_cast<unsigned short*>(&b);
}

// ===== fused conversion + epilogue-precompute + gat-pad-zero + CSR-count kernel =====
struct bf4 { __hip_bfloat16 a, b, c, d; };

#define NWQ4 ((MPADQ * 512) / 4)        // 2,572,288
#define NXE4 ((B_ * S_ * D_) / 4)       //    98,304
#define NWL4 ((F_ * D_) / 4)            //    36,864
#define NWP4 ((S_ * N_) / 4)            // 2,560,000
#define NWT4 ((DG_ * F_) / 4)           //    12,288
#define NCV0 NWQ4
#define NCV1 (NCV0 + NXE4)
#define NCV2 (NCV1 + NWL4)
#define NCV3 (NCV2 + NWP4)
#define NCV4 (NCV3 + NWT4)              // 5,279,744 (multiple of 64)
#define NCV5 (NCV4 + (F_ + DG_) * 64)   // + prep waves: 5,312,512 (mult of 256)
#define NZP4 (((MPADL - BN_) * F_) / 8) // gat pad zero, int4 units: 3072 (mult of 256)
#define NCV6 (NCV5 + NZP4)              // 5,315,584 (mult of 256)
#define NCV7 (NCV6 + E_)                // 5,635,584 (mult of 256)

__device__ __forceinline__ void cv4(const float* __restrict__ src,
                                    __hip_bfloat16* __restrict__ dst, int e) {
  float4 v = *(const float4*)(src + e);
  bf4 r{__float2bfloat16(v.x), __float2bfloat16(v.y),
        __float2bfloat16(v.z), __float2bfloat16(v.w)};
  *(bf4*)(dst + e) = r;
}

// epi[0][f] = sum_d Wlin[f,d]          (multiplies bq[n])
// epi[1][f] = sum_d Wm[d]*Wlin[f,d]    (multiplies mask[b,n])
// epi[2][f] = sum_d bm[d]*Wlin[f,d]    (constant)
// swt[g]    = sum_f Wtemp[g,f]         (multiplies bproj[s] in final)
// tail regions: zero gat pad rows; CSR degree count (counts memset'd beforehand)
__global__ __launch_bounds__(256) void conv_all_kernel(
    const float* __restrict__ Wq,    __hip_bfloat16* __restrict__ WqB,
    const float* __restrict__ xe,    __hip_bfloat16* __restrict__ xeB,
    const float* __restrict__ Wlin,  __hip_bfloat16* __restrict__ WlinB,
    const float* __restrict__ Wproj, __hip_bfloat16* __restrict__ WprojB,
    const float* __restrict__ Wtemp, __hip_bfloat16* __restrict__ WtempB,
    const float* __restrict__ Wm,    const float* __restrict__ bm,
    float* __restrict__ epi,         float* __restrict__ swt,
    __hip_bfloat16* __restrict__ gat, const int* __restrict__ ei,
    int* __restrict__ counts,        int* __restrict__ rank) {
  int idx = blockIdx.x * 256 + threadIdx.x;
  if (idx < NCV0) {
    int e = idx * 4;
    int row = e >> 9;                       // Wq row (ld 512)
    float4 v = make_float4(0.f, 0.f, 0.f, 0.f);
    if (row < N_) v = *(const float4*)(Wq + e);
    bf4 r{__float2bfloat16(v.x), __float2bfloat16(v.y),
          __float2bfloat16(v.z), __float2bfloat16(v.w)};
    *(bf4*)(WqB + e) = r;
  } else if (idx < NCV1) {
    cv4(xe, xeB, (idx - NCV0) * 4);
  } else if (idx < NCV2) {
    cv4(Wlin, WlinB, (idx - NCV1) * 4);
  } else if (idx < NCV3) {
    cv4(Wproj, WprojB, (idx - NCV2) * 4);
  } else if (idx < NCV4) {
    cv4(Wtemp, WtempB, (idx - NCV3) * 4);
  } else if (idx < NCV5) {
    // prep region: wave-aligned (NCV4 % 64 == 0); one wave per output row
    int w = (idx - NCV4) >> 6;
    int lane = idx & 63;
    if (w < F_) {
      float s0 = 0.f, s1 = 0.f, s2 = 0.f;
      const float* row = Wlin + (size_t)w * D_;
      for (int d = lane; d < D_; d += 64) {
        float wv = row[d];
        s0 += wv; s1 += Wm[d] * wv; s2 += bm[d] * wv;
      }
#pragma unroll
      for (int o = 32; o > 0; o >>= 1) {
        s0 += __shfl_down(s0, o); s1 += __shfl_down(s1, o); s2 += __shfl_down(s2, o);
      }
      if (lane == 0) { epi[w] = s0; epi[F_ + w] = s1; epi[2 * F_ + w] = s2; }
    } else {
      int g = w - F_;
      float s = 0.f;
      const float* row = Wtemp + (size_t)g * F_;
      for (int f = lane; f < F_; f += 64) s += row[f];
#pragma unroll
      for (int o = 32; o > 0; o >>= 1) s += __shfl_down(s, o);
      if (lane == 0) swt[g] = s;
    }
  } else if (idx < NCV6) {
    // zero gat pad rows (read by gemm_gn A-loads much later; outputs discarded)
    int e = (idx - NCV5) * 8;
    *(int4*)((unsigned short*)gat + (size_t)BN_ * F_ + e) = make_int4(0, 0, 0, 0);
  } else if (idx < NCV7) {
    // CSR degree count (counts zeroed by preceding memset on the same stream)
    int eidx = idx - NCV6;
    int d = ei[E_ + eidx];
    rank[eidx] = atomicAdd(&counts[d], 1);
  }
}

// ================= bf16 MFMA GEMM (NT: A[m][k], Bt[n][k], both k-major) =================
// EPI=1: xp epilogue  v += bq[rg]*epi[cg] + mask[bz*N+rg]*epi[F+cg] + epi[2F+cg]
template <int EPI>
__global__ __launch_bounds__(256) void mfma_gemm_nt(
    const __hip_bfloat16* __restrict__ A, const __hip_bfloat16* __restrict__ Bt,
    __hip_bfloat16* __restrict__ Cout, int K, int Mvalid, int ldc,
    size_t bstrideB, size_t bstrideC,
    const float* __restrict__ bq, const float* __restrict__ mask,
    const float* __restrict__ epi) {
  const int tid = threadIdx.x;
  const int m0 = blockIdx.x * 128;
  const int n0 = blockIdx.y * 128;
  const int bz = blockIdx.z;

  const unsigned short* Ap = (const unsigned short*)A;
  const unsigned short* Bp = (const unsigned short*)(Bt + bstrideB * bz);

  __shared__ __align__(16) unsigned short As[128][40];
  __shared__ __align__(16) unsigned short Bs[128][40];

  const int wave = tid >> 6, lane = tid & 63;
  const int wm = (wave & 1) * 64, wn = (wave >> 1) * 64;
  const int lrow = lane & 15, lk = (lane >> 4) * 8;

  const int srow = tid >> 2;            // 0..63
  const int skoff = (tid & 3) * 8;      // 0,8,16,24

  floatx4 acc[4][4];
#pragma unroll
  for (int i = 0; i < 4; ++i)
#pragma unroll
    for (int j = 0; j < 4; ++j) acc[i][j] = floatx4{0.f, 0.f, 0.f, 0.f};

  for (int k0 = 0; k0 < K; k0 += 32) {
    int4 av0 = *(const int4*)(Ap + (size_t)(m0 + srow) * K + k0 + skoff);
    int4 av1 = *(const int4*)(Ap + (size_t)(m0 + 64 + srow) * K + k0 + skoff);
    int4 bv0 = *(const int4*)(Bp + (size_t)(n0 + srow) * K + k0 + skoff);
    int4 bv1 = *(const int4*)(Bp + (size_t)(n0 + 64 + srow) * K + k0 + skoff);
    __syncthreads();
    *(int4*)&As[srow][skoff] = av0;
    *(int4*)&As[64 + srow][skoff] = av1;
    *(int4*)&Bs[srow][skoff] = bv0;
    *(int4*)&Bs[64 + srow][skoff] = bv1;
    __syncthreads();
    short8 af[4], bf[4];
#pragma unroll
    for (int mt = 0; mt < 4; ++mt)
      af[mt] = *(const short8*)&As[wm + mt * 16 + lrow][lk];
#pragma unroll
    for (int nt = 0; nt < 4; ++nt)
      bf[nt] = *(const short8*)&Bs[wn + nt * 16 + lrow][lk];
#pragma unroll
    for (int mt = 0; mt < 4; ++mt)
#pragma unroll
      for (int nt = 0; nt < 4; ++nt)
        acc[mt][nt] = __builtin_amdgcn_mfma_f32_16x16x32_bf16(af[mt], bf[nt],
                                                              acc[mt][nt], 0, 0, 0);
  }

  __hip_bfloat16* Cb = Cout + bstrideC * bz;
#pragma unroll
  for (int mt = 0; mt < 4; ++mt) {
#pragma unroll
    for (int r = 0; r < 4; ++r) {
      int rg = m0 + wm + mt * 16 + (lane >> 4) * 4 + r;
      if (rg < Mvalid) {
        float bqv = 0.f, mkv = 0.f;
        if (EPI) {
          bqv = bq[rg];
          mkv = mask[bz * N_ + rg];
        }
#pragma unroll
        for (int nt = 0; nt < 4; ++nt) {
          int cg = n0 + wn + nt * 16 + lrow;
          float v = acc[mt][nt][r];
          if (EPI) v += bqv * epi[cg] + mkv * epi[F_ + cg] + epi[2 * F_ + cg];
          Cb[(size_t)rg * ldc + cg] = __float2bfloat16(v);
        }
      }
    }
  }
}

// ================= gn = gat · Wtemp^T, output TRANSPOSED to gnT [b][g][n] =================
// A = gat [MPADL][F] (rows >= BN_ zeroed, discarded), B = WtempB [DG][F], K=F
__global__ __launch_bounds__(256) void gemm_gn(
    const __hip_bfloat16* __restrict__ A, const __hip_bfloat16* __restrict__ Bt,
    __hip_bfloat16* __restrict__ gnT) {
  const int tid = threadIdx.x;
  const int m0 = blockIdx.x * 128;

  const unsigned short* Ap = (const unsigned short*)A;
  const unsigned short* Bp = (const unsigned short*)Bt;

  __shared__ __align__(16) unsigned short As[128][40];
  __shared__ __align__(16) unsigned short Bs[128][40];

  const int wave = tid >> 6, lane = tid & 63;
  const int wm = (wave & 1) * 64, wn = (wave >> 1) * 64;
  const int lrow = lane & 15, lk = (lane >> 4) * 8;
  const int srow = tid >> 2;
  const int skoff = (tid & 3) * 8;

  floatx4 acc[4][4];
#pragma unroll
  for (int i = 0; i < 4; ++i)
#pragma unroll
    for (int j = 0; j < 4; ++j) acc[i][j] = floatx4{0.f, 0.f, 0.f, 0.f};

  for (int k0 = 0; k0 < F_; k0 += 32) {
    int4 av0 = *(const int4*)(Ap + (size_t)(m0 + srow) * F_ + k0 + skoff);
    int4 av1 = *(const int4*)(Ap + (size_t)(m0 + 64 + srow) * F_ + k0 + skoff);
    int4 bv0 = *(const int4*)(Bp + (size_t)(srow) * F_ + k0 + skoff);
    int4 bv1 = *(const int4*)(Bp + (size_t)(64 + srow) * F_ + k0 + skoff);
    __syncthreads();
    *(int4*)&As[srow][skoff] = av0;
    *(int4*)&As[64 + srow][skoff] = av1;
    *(int4*)&Bs[srow][skoff] = bv0;
    *(int4*)&Bs[64 + srow][skoff] = bv1;
    __syncthreads();
    short8 af[4], bf[4];
#pragma unroll
    for (int mt = 0; mt < 4; ++mt)
      af[mt] = *(const short8*)&As[wm + mt * 16 + lrow][lk];
#pragma unroll
    for (int nt = 0; nt < 4; ++nt)
      bf[nt] = *(const short8*)&Bs[wn + nt * 16 + lrow][lk];
#pragma unroll
    for (int mt = 0; mt < 4; ++mt)
#pragma unroll
      for (int nt = 0; nt < 4; ++nt)
        acc[mt][nt] = __builtin_amdgcn_mfma_f32_16x16x32_bf16(af[mt], bf[nt],
                                                              acc[mt][nt], 0, 0, 0);
  }

  // transposed store: 4 consecutive rows (one r-group) -> 4 consecutive n in gnT
#pragma unroll
  for (int mt = 0; mt < 4; ++mt) {
    int rg0 = m0 + wm + mt * 16 + (lane >> 4) * 4;
    if (rg0 < BN_) {                      // rg0 mult of 4, BN_/N_ mult of 4
      int b = (rg0 >= N_) ? 1 : 0;
      int n = rg0 - b * N_;
#pragma unroll
      for (int nt = 0; nt < 4; ++nt) {
        int cg = wn + nt * 16 + lrow;     // 0..127
        ushort4 o;
        o.x = f2b(acc[mt][nt][0]); o.y = f2b(acc[mt][nt][1]);
        o.z = f2b(acc[mt][nt][2]); o.w = f2b(acc[mt][nt][3]);
        *(ushort4*)((unsigned short*)gnT + (size_t)b * DG_ * N_ + (size_t)cg * N_ + n) = o;
      }
    }
  }
}

// ================= proj2: Wproj · gn^T, split-K over N_, fp32 partials =================
// A = WprojB [S][N_], B = gnT[b] [DG][N_], out Ppart[bz][S][DG]
__global__ __launch_bounds__(256) void gemm_proj2(
    const __hip_bfloat16* __restrict__ A, const __hip_bfloat16* __restrict__ Bt,
    float* __restrict__ Ppart) {
  const int tid = threadIdx.x;
  const int m0 = blockIdx.x * 128;       // s tile
  const int bz = blockIdx.z;             // b*PNS2 + ks
  const int b = bz / PNS2, ks = bz - b * PNS2;
  const int kbeg = ks * PCH2;
  const int kend = (kbeg + PCH2 < N_) ? (kbeg + PCH2) : N_;

  const unsigned short* Ap = (const unsigned short*)A;
  const unsigned short* Bp = (const unsigned short*)(Bt + (size_t)b * DG_ * N_);

  __shared__ __align__(16) unsigned short As[128][40];
  __shared__ __align__(16) unsigned short Bs[128][40];

  const int wave = tid >> 6, lane = tid & 63;
  const int wm = (wave & 1) * 64, wn = (wave >> 1) * 64;
  const int lrow = lane & 15, lk = (lane >> 4) * 8;
  const int srow = tid >> 2;
  const int skoff = (tid & 3) * 8;

  floatx4 acc[4][4];
#pragma unroll
  for (int i = 0; i < 4; ++i)
#pragma unroll
    for (int j = 0; j < 4; ++j) acc[i][j] = floatx4{0.f, 0.f, 0.f, 0.f};

  for (int k0 = kbeg; k0 < kend; k0 += 32) {
    int4 av0 = *(const int4*)(Ap + (size_t)(m0 + srow) * N_ + k0 + skoff);
    int4 av1 = *(const int4*)(Ap + (size_t)(m0 + 64 + srow) * N_ + k0 + skoff);
    int4 bv0 = *(const int4*)(Bp + (size_t)(srow) * N_ + k0 + skoff);
    int4 bv1 = *(const int4*)(Bp + (size_t)(64 + srow) * N_ + k0 + skoff);
    __syncthreads();
    *(int4*)&As[srow][skoff] = av0;
    *(int4*)&As[64 + srow][skoff] = av1;
    *(int4*)&Bs[srow][skoff] = bv0;
    *(int4*)&Bs[64 + srow][skoff] = bv1;
    __syncthreads();
    short8 af[4], bf[4];
#pragma unroll
    for (int mt = 0; mt < 4; ++mt)
      af[mt] = *(const short8*)&As[wm + mt * 16 + lrow][lk];
#pragma unroll
    for (int nt = 0; nt < 4; ++nt)
      bf[nt] = *(const short8*)&Bs[wn + nt * 16 + lrow][lk];
#pragma unroll
    for (int mt = 0; mt < 4; ++mt)
#pragma unroll
      for (int nt = 0; nt < 4; ++nt)
        acc[mt][nt] = __builtin_amdgcn_mfma_f32_16x16x32_bf16(af[mt], bf[nt],
                                                              acc[mt][nt], 0, 0, 0);
  }

  float* Pp = Ppart + (size_t)bz * S_ * DG_;
#pragma unroll
  for (int mt = 0; mt < 4; ++mt) {
#pragma unroll
    for (int r = 0; r < 4; ++r) {
      int rg = m0 + wm + mt * 16 + (lane >> 4) * 4 + r;   // < 512 always
#pragma unroll
      for (int nt = 0; nt < 4; ++nt) {
        int cg = wn + nt * 16 + lrow;                      // < 128
        Pp[(size_t)rg * DG_ + cg] = acc[mt][nt][r];
      }
    }
  }
}

// ---------------- attention coefficients ----------------
__global__ __launch_bounds__(256) void att_kernel(
    const __hip_bfloat16* __restrict__ xp, const float* __restrict__ att_src,
    const float* __restrict__ att_dst, float* __restrict__ a_src,
    float* __restrict__ a_dst) {
  int gid = blockIdx.x * blockDim.x + threadIdx.x;
  int wid = gid >> 6;
  int lane = threadIdx.x & 63;
  if (wid >= BN_ * H_) return;
  int i = wid / H_, h = wid - i * H_;
  const __hip_bfloat16* row = xp + (size_t)i * F_ + h * C_;
  const float* as = att_src + h * C_;
  const float* ad = att_dst + h * C_;
  float v0 = __bfloat162float(row[lane]), v1 = __bfloat162float(row[lane + 64]);
  float s1 = v0 * as[lane] + v1 * as[lane + 64];
  float s2 = v0 * ad[lane] + v1 * ad[lane + 64];
#pragma unroll
  for (int off = 32; off > 0; off >>= 1) {
    s1 += __shfl_down(s1, off);
    s2 += __shfl_down(s2, off);
  }
  if (lane == 0) {
    a_src[i * H_ + h] = s1;
    a_dst[i * H_ + h] = s2;
  }
}

// hierarchical scan over N_: scan1 (per-block) -> scan23 (base scan + add)
#define SCB 1024
#define NSCB ((N_ + SCB - 1) / SCB)     // 20
__global__ __launch_bounds__(1024) void scan1_kernel(const int* __restrict__ counts,
                                                     int* __restrict__ offs,
                                                     int* __restrict__ btot) {
  __shared__ int wsum[16];
  int t = threadIdx.x, wave = t >> 6, lane = t & 63;
  int i = blockIdx.x * SCB + t;
  int v = (i < N_) ? (counts[i] + 1) : 0;  // +1 = self loop
  int x = v;
#pragma unroll
  for (int o = 1; o < 64; o <<= 1) {
    int y = __shfl_up(x, o);
    if (lane >= o) x += y;
  }
  if (lane == 63) wsum[wave] = x;
  __syncthreads();
  if (wave == 0) {
    int w = (lane < 16) ? wsum[lane] : 0;
#pragma unroll
    for (int o = 1; o < 16; o <<= 1) {
      int y = __shfl_up(w, o);
      if (lane >= o) w += y;
    }
    if (lane < 16) wsum[lane] = w;
  }
  __syncthreads();
  int woff = (wave == 0) ? 0 : wsum[wave - 1];
  if (i < N_) offs[i] = woff + x - v;      // exclusive within block
  if (t == 0) btot[blockIdx.x] = wsum[15];
}

// scan the 20 block totals (thread 0, trivial) then add base to offs
__global__ __launch_bounds__(1024) void scan23_kernel(int* __restrict__ offs,
                                                      const int* __restrict__ btot) {
  __shared__ int sb[NSCB];
  int t = threadIdx.x;
  if (t == 0) {
    int run = 0;
    for (int k = 0; k < NSCB; ++k) { sb[k] = run; run += btot[k]; }
  }
  __syncthreads();
  for (int base = 0; base < N_; base += 1024) {
    int i = base + t;
    if (i < N_) offs[i] += sb[i >> 10];
  }
}

__global__ __launch_bounds__(256) void fill_kernel(
    const int* __restrict__ ei, const int* __restrict__ rank,
    const int* __restrict__ offs, const int* __restrict__ counts,
    int* __restrict__ col) {
  int idx = blockIdx.x * blockDim.x + threadIdx.x;
  if (idx >= ECSR_) return;
  if (idx < E_) {
    int sg = ei[idx];
    int dg = ei[E_ + idx];
    col[offs[dg] + rank[idx]] = sg;     // local src index
  } else {
    int n = idx - E_;
    col[offs[n] + counts[n]] = n;       // self loop
  }
}

// ---------------- aggregation: one (node, batch) per block; inline softmax -------
// blockIdx 0..N-1: batch 0, N..2N-1: batch 1 (batch-contiguous dispatch keeps each
// 15.4MB xp half hot in L2/L3). 96 active threads: thread t covers xp columns
// [t*4, t*4+4), head h = t/32. Denominator is free: all 32 threads of a head-group
// compute the identical w per edge.
__global__ __launch_bounds__(128) void agg_kernel(
    const int* __restrict__ offs, const int* __restrict__ counts,
    const int* __restrict__ col, const float* __restrict__ a_src,
    const float* __restrict__ a_dst, const __hip_bfloat16* __restrict__ xp,
    const float* __restrict__ bias_gat, __hip_bfloat16* __restrict__ out) {
  int bi = blockIdx.x;
  int q = (bi >= N_) ? 1 : 0;
  int n = bi - q * N_;
  int qn = q * N_;
  int i = qn + n;
  int t = threadIdx.x;
  if (t >= 96) return;
  int beg = offs[n];
  int nE = counts[n] + 1;
  int h = t >> 5;

  const ushort4* xp4 = (const ushort4*)xp;   // row stride 96 ushort4
  float ad = a_dst[(size_t)i * 3 + h];
  float ax = 0.f, ay = 0.f, az = 0.f, aw = 0.f, sw = 0.f;

  int j = 0;
  for (; j + 4 <= nE; j += 4) {
    int s0 = col[beg + j + 0] + qn;
    int s1 = col[beg + j + 1] + qn;
    int s2 = col[beg + j + 2] + qn;
    int s3 = col[beg + j + 3] + qn;
    float e0 = a_src[(size_t)s0 * 3 + h] + ad;
    float e1 = a_src[(size_t)s1 * 3 + h] + ad;
    float e2 = a_src[(size_t)s2 * 3 + h] + ad;
    float e3 = a_src[(size_t)s3 * 3 + h] + ad;
    e0 = (e0 > 0.f) ? e0 : 0.2f * e0;
    e1 = (e1 > 0.f) ? e1 : 0.2f * e1;
    e2 = (e2 > 0.f) ? e2 : 0.2f * e2;
    e3 = (e3 > 0.f) ? e3 : 0.2f * e3;
    float w0 = __expf(e0), w1 = __expf(e1);
    float w2 = __expf(e2), w3 = __expf(e3);
    sw += (w0 + w1) + (w2 + w3);
    ushort4 v0 = xp4[(size_t)s0 * 96 + t];
    ushort4 v1 = xp4[(size_t)s1 * 96 + t];
    ushort4 v2 = xp4[(size_t)s2 * 96 + t];
    ushort4 v3 = xp4[(size_t)s3 * 96 + t];
    ax = fmaf(w0, b2f(v0.x), ax); ay = fmaf(w0, b2f(v0.y), ay);
    az = fmaf(w0, b2f(v0.z), az); aw = fmaf(w0, b2f(v0.w), aw);
    ax = fmaf(w1, b2f(v1.x), ax); ay = fmaf(w1, b2f(v1.y), ay);
    az = fmaf(w1, b2f(v1.z), az); aw = fmaf(w1, b2f(v1.w), aw);
    ax = fmaf(w2, b2f(v2.x), ax); ay = fmaf(w2, b2f(v2.y), ay);
    az = fmaf(w2, b2f(v2.z), az); aw = fmaf(w2, b2f(v2.w), aw);
    ax = fmaf(w3, b2f(v3.x), ax); ay = fmaf(w3, b2f(v3.y), ay);
    az = fmaf(w3, b2f(v3.z), az); aw = fmaf(w3, b2f(v3.w), aw);
  }
  for (; j < nE; ++j) {
    int s0 = col[beg + j] + qn;
    float e0 = a_src[(size_t)s0 * 3 + h] + ad;
    e0 = (e0 > 0.f) ? e0 : 0.2f * e0;
    float w0 = __expf(e0);
    sw += w0;
    ushort4 v0 = xp4[(size_t)s0 * 96 + t];
    ax = fmaf(w0, b2f(v0.x), ax); ay = fmaf(w0, b2f(v0.y), ay);
    az = fmaf(w0, b2f(v0.z), az); aw = fmaf(w0, b2f(v0.w), aw);
  }

  float r = 1.0f / sw;
  const float4 bg = *(const float4*)(bias_gat + t * 4);
  ushort4 o;
  o.x = f2b(ax * r + bg.x);
  o.y = f2b(ay * r + bg.y);
  o.z = f2b(az * r + bg.z);
  o.w = f2b(aw * r + bg.w);
  *(ushort4*)((unsigned short*)out + (size_t)i * F_ + t * 4) = o;
}

// ---------------- final: reduce split-K partials + analytic bproj/btemp ----------------
__global__ __launch_bounds__(128) void final_kernel(
    const float* __restrict__ Ppart, const float* __restrict__ bproj,
    const float* __restrict__ swt, const float* __restrict__ btemp,
    float* __restrict__ out) {
  int bs = blockIdx.x;          // 0..B*S-1
  int b = bs >> 9;
  int s = bs & (S_ - 1);
  int g = threadIdx.x;
  float acc = btemp[g] + bproj[s] * swt[g];
  const float* pp = Ppart + ((size_t)b * PNS2 * S_ + s) * DG_ + g;
  for (int ns = 0; ns < PNS2; ++ns) acc += pp[(size_t)ns * S_ * DG_];
  out[(size_t)bs * DG_ + g] = acc;
}

// ---------------- launcher ----------------
extern "C" void kernel_launch(void* const* d_in, const int* in_sizes, int n_in,
                              void* d_out, int out_size, void* d_ws, size_t ws_size,
                              hipStream_t stream) {
  const float* x_enc   = (const float*)d_in[0];
  const float* mask    = (const float*)d_in[1];
  const int*   ei      = (const int*)d_in[2];
  const float* Wq      = (const float*)d_in[3];
  const float* bq      = (const float*)d_in[4];
  const float* Wm      = (const float*)d_in[5];
  const float* bm      = (const float*)d_in[6];
  const float* Wlin    = (const float*)d_in[7];
  const float* att_src = (const float*)d_in[8];
  const float* att_dst = (const float*)d_in[9];
  const float* bias_gat= (const float*)d_in[10];
  const float* Wproj   = (const float*)d_in[11];
  const float* bproj   = (const float*)d_in[12];
  const float* Wtemp   = (const float*)d_in[13];
  const float* btemp   = (const float*)d_in[14];
  float* outp = (float*)d_out;

  char* ws = (char*)d_ws;
  size_t off = 0;
  auto alloc = [&](size_t bytes) {
    char* p = ws + off;
    off = (off + bytes + 255) & ~(size_t)255;
    return p;
  };

  // regionA timeline:
  //   phase 1 (conv/gemm_q):   Wq_b bf16 [0, 20.58M)
  //   phase 2 (gemm_gn):       gnT bf16 at [16.78M, 27.02M)   (Wq_b dead)
  //   phase 3 (gemm_proj2):    Ppart fp32 [0, 16.78M)         (reads gnT)
  const size_t GNT_OFF = (size_t)B_ * PNS2 * S_ * DG_ * 4;   // 16,777,216
  char* regionA = alloc(GNT_OFF + (size_t)B_ * DG_ * N_ * 2);  // 27.02 MB
  __hip_bfloat16* Wq_b = (__hip_bfloat16*)regionA;
  float* Ppart = (float*)regionA;
  __hip_bfloat16* gnT  = (__hip_bfloat16*)(regionA + GNT_OFF);

  __hip_bfloat16* xeB    = (__hip_bfloat16*)alloc((size_t)B_ * S_ * D_ * 2);
  __hip_bfloat16* yT     = (__hip_bfloat16*)alloc((size_t)B_ * F_ * S_ * 2);
  __hip_bfloat16* xp     = (__hip_bfloat16*)alloc((size_t)BN_ * F_ * 2);
  __hip_bfloat16* gat    = (__hip_bfloat16*)alloc((size_t)MPADL * F_ * 2);  // padded rows
  __hip_bfloat16* WlinB  = (__hip_bfloat16*)alloc((size_t)F_ * D_ * 2);
  __hip_bfloat16* WprojB = (__hip_bfloat16*)alloc((size_t)S_ * N_ * 2);
  __hip_bfloat16* WtempB = (__hip_bfloat16*)alloc((size_t)DG_ * F_ * 2);
  float* epi   = (float*)alloc((size_t)3 * F_ * 4);
  float* swt   = (float*)alloc((size_t)DG_ * 4);
  float* a_src = (float*)alloc((size_t)BN_ * H_ * 4);
  float* a_dst = (float*)alloc((size_t)BN_ * H_ * 4);
  int* counts  = (int*)alloc((size_t)N_ * 4);
  int* offsb   = (int*)alloc((size_t)N_ * 4);
  int* rank    = (int*)alloc((size_t)E_ * 4);
  int* col     = (int*)alloc((size_t)ECSR_ * 4);
  int* btot    = (int*)alloc((size_t)NSCB * 4);
  if (off > ws_size) return;  // workspace too small: fail loudly via absmax

  hipMemsetAsync(counts, 0, (size_t)N_ * 4, stream);

  // conversions + epi/swt precompute + gat-pad zero + CSR degree count (one launch)
  conv_all_kernel<<<NCV7 / 256, 256, 0, stream>>>(
      Wq, Wq_b, x_enc, xeB, Wlin, WlinB, Wproj, WprojB, Wtemp, WtempB,
      Wm, bm, epi, swt, gat, ei, counts, rank);

  // CSR offsets + fill
  scan1_kernel<<<NSCB, SCB, 0, stream>>>(counts, offsb, btot);
  scan23_kernel<<<1, 1024, 0, stream>>>(offsb, btot);
  fill_kernel<<<(ECSR_ + 255) / 256, 256, 0, stream>>>(ei, rank, offsb, counts, col);

  // y^T[b][f][s] = sum_d Wlin[f,d] * xe[b,s,d]   (tiny GEMM, 0.3 GF)
  mfma_gemm_nt<0><<<dim3(F_ / 128, S_ / 128, B_), 256, 0, stream>>>(
      WlinB, xeB, yT, D_, F_, S_, (size_t)S_ * D_, (size_t)F_ * S_,
      nullptr, nullptr, nullptr);
  // xp[b,n,f] = sum_s Wq[n,s]*y[b,s,f] + bq[n]*sWl[f] + mask[b,n]*wmW[f] + bmW[f]
  mfma_gemm_nt<1><<<dim3(MPADQ / 128, F_ / 128, B_), 256, 0, stream>>>(
      Wq_b, yT, xp, S_, N_, F_, (size_t)F_ * S_, (size_t)N_ * F_,
      bq, mask, epi);

  att_kernel<<<(BN_ * H_ + 3) / 4, 256, 0, stream>>>(xp, att_src, att_dst, a_src, a_dst);
  agg_kernel<<<BN_, 128, 0, stream>>>(offsb, counts, col, a_src, a_dst,
                                      xp, bias_gat, gat);

  // gn^T[b][g][n] = sum_f gat[b,n,f] * Wtemp[g,f]   (3.9 GF, transposed store)
  gemm_gn<<<dim3(MPADL / 128, 1, 1), 256, 0, stream>>>(gat, WtempB, gnT);
  // Ppart[bz][s][g] = sum_{k in chunk} Wproj[s,k] * gn[b,k,g]
  gemm_proj2<<<dim3(S_ / 128, 1, B_ * PNS2), 256, 0, stream>>>(WprojB, gnT, Ppart);
  // out[b,s,g] = sum_ks Ppart + bproj[s]*swt[g] + btemp[g]
  final_kernel<<<B_ * S_, 128, 0, stream>>>(Ppart, bproj, swt, btemp, outp);
}